// Round 3
// baseline (1512.813 us; speedup 1.0000x reference)
//
#include <hip/hip_runtime.h>
#include <stdint.h>

// Viterbi CRF decode, batch element 63 only (reference returns scores[-1], paths[-1]).
// feats: [64,1024,512] f32, transitions: [512,512] f32, lengths: [64] int.
// out: [0]=score (f32), [1..1024]=path as f32 (-1 for t>=len).
//
// Protocol: 512 waves, one destination row each. fv exchanged via an 8-deep
// ring of 512 packed (tag<<32 | f32) words in ws, relaxed agent-scope atomics
// only (payload rides with the tag in one word; no ordering needed). No
// barriers, no read-gate: slot-t fully fresh implies every wave finished step
// t-1, hence finished reading all older slots -> overwrite is safe.
// Lane l owns candidates j = l + 64m (m=0..7): spin loads, transitions slice,
// and argmax are all lane-local; one 6-level shuffle reduce per step.

#define KK 512
#define TMAX 1024
#define STARTT 510
#define STOPT 511
#define NEGINF (-10000.0f)
#define DSLOT 8

// ws layout
#define WS_FV 0                      // uint64 fvbuf[8][512]  (32 KB)
#define WS_BEST 32768                // int best
#define WS_BP 40960                  // uint16 bp[1024][512]  (1 MB)
#define WS_E (40960 + 1048576)       // uint16 E[64][512]     (64 KB)

__device__ __forceinline__ int read_len(const void* lp) {
  // lengths may be int32 or int64; int64 little-endian has hi-word 0 at odd int32 slots
  const int* q = (const int*)lp;
  return (q[1] == 0) ? (int)(((const long long*)lp)[63]) : q[63];
}

__global__ void k_init(char* ws) {
  uint64_t* fvb = (uint64_t*)(ws + WS_FV);
  int tid = threadIdx.x;  // 512
  float v = (tid == STARTT) ? 0.0f : NEGINF;
  fvb[tid] = (uint64_t)__float_as_uint(v);  // tag 0 in hi32
#pragma unroll
  for (int b = 1; b < DSLOT; ++b) fvb[b * KK + tid] = 0x7FFFFFFF00000000ull;
}

__global__ void __launch_bounds__(64) k_forward(
    const float* __restrict__ feats, const float* __restrict__ trans,
    const void* __restrict__ lens, float* __restrict__ out, char* ws) {
  const int len = read_len(lens);
  const int R = blockIdx.x;   // 0..511, my destination row
  const int l = threadIdx.x;  // 0..63
  uint64_t* fvb = (uint64_t*)(ws + WS_FV);
  uint16_t* bp = (uint16_t*)(ws + WS_BP);

  // transitions slice in registers: row R, cols l+64m
  float tr[8];
#pragma unroll
  for (int m = 0; m < 8; ++m) tr[m] = trans[(size_t)R * KK + l + 64 * m];

  const float* fb = feats + 63ll * TMAX * KK;  // batch 63
  float featNext = fb[R];  // same addr all lanes -> broadcast

  for (int t = 0; t < len; ++t) {
    uint64_t* slot = fvb + (size_t)(t & (DSLOT - 1)) * KK;
    uint64_t v[8];
    bool ok;
    do {
#pragma unroll
      for (int m = 0; m < 8; ++m)
        v[m] = __hip_atomic_load(&slot[l + 64 * m], __ATOMIC_RELAXED, __HIP_MEMORY_SCOPE_AGENT);
      ok = true;
#pragma unroll
      for (int m = 0; m < 8; ++m) ok = ok && ((int)(uint32_t)(v[m] >> 32) == t);
    } while (__any(!ok));

    const float featCur = featNext;
    if (t + 1 < len) featNext = fb[(size_t)(t + 1) * KK + R];

    // candidates j = l + 64m, lane-local
    float c0[8];
#pragma unroll
    for (int m = 0; m < 8; ++m) c0[m] = __uint_as_float((uint32_t)v[m]) + tr[m];
    // tree argmax within lane; ">=" prefers lower m => lower j (first-index ties)
    float v4[4]; int i4[4];
#pragma unroll
    for (int m = 0; m < 4; ++m) {
      const bool L = c0[2 * m] >= c0[2 * m + 1];
      v4[m] = L ? c0[2 * m] : c0[2 * m + 1];
      i4[m] = L ? 2 * m : 2 * m + 1;
    }
    float v2[2]; int i2[2];
#pragma unroll
    for (int m = 0; m < 2; ++m) {
      const bool L = v4[2 * m] >= v4[2 * m + 1];
      v2[m] = L ? v4[2 * m] : v4[2 * m + 1];
      i2[m] = L ? i4[2 * m] : i4[2 * m + 1];
    }
    const bool L = v2[0] >= v2[1];
    float bv = L ? v2[0] : v2[1];
    int bj = l + 64 * (L ? i2[0] : i2[1]);
    // cross-lane reduce, first-index tie-break
#pragma unroll
    for (int m = 32; m >= 1; m >>= 1) {
      float ov = __shfl_xor(bv, m);
      int oj = __shfl_xor(bj, m);
      if (ov > bv || (ov == bv && oj < bj)) { bv = ov; bj = oj; }
    }
    if (l == 0) {
      const float vit = bv + featCur;
      const uint64_t pk = ((uint64_t)(uint32_t)(t + 1) << 32) | (uint64_t)__float_as_uint(vit);
      __hip_atomic_store(&fvb[(size_t)((t + 1) & (DSLOT - 1)) * KK + R], pk,
                         __ATOMIC_RELAXED, __HIP_MEMORY_SCOPE_AGENT);
      bp[(size_t)t * KK + R] = (uint16_t)bj;  // after fv store: off critical path
    }
  }

  if (R != 0) return;
  // terminal: score = max_j fv[j] + trans[STOP][j], best = first argmax
  {
    uint64_t* slot = fvb + (size_t)(len & (DSLOT - 1)) * KK;
    uint64_t v[8];
    bool ok;
    do {
#pragma unroll
      for (int m = 0; m < 8; ++m)
        v[m] = __hip_atomic_load(&slot[l + 64 * m], __ATOMIC_RELAXED, __HIP_MEMORY_SCOPE_AGENT);
      ok = true;
#pragma unroll
      for (int m = 0; m < 8; ++m) ok = ok && ((int)(uint32_t)(v[m] >> 32) == len);
    } while (__any(!ok));
    float tv;
    int tj;
#pragma unroll
    for (int m = 0; m < 8; ++m) {
      float x = __uint_as_float((uint32_t)v[m]) + trans[(size_t)STOPT * KK + l + 64 * m];
      if (m == 0) {
        tv = x; tj = l;
      } else if (x > tv) {
        tv = x; tj = l + 64 * m;
      }
    }
#pragma unroll
    for (int m = 32; m >= 1; m >>= 1) {
      float ov = __shfl_xor(tv, m);
      int oj = __shfl_xor(tj, m);
      if (ov > tv || (ov == tv && oj < tj)) { tv = ov; tj = oj; }
    }
    if (l == 0) {
      out[0] = tv;
      *((int*)(ws + WS_BEST)) = tj;
    }
  }
}

// speculative backtrack: per 16-step segment, walk all 512 possible entry tags
__global__ void __launch_bounds__(512) k_walk(const void* __restrict__ lens, char* ws) {
  const int len = read_len(lens);
  const uint16_t* bp = (const uint16_t*)(ws + WS_BP);
  uint16_t* E = (uint16_t*)(ws + WS_E);
  const int s = blockIdx.x;   // 64 segments
  const int k = threadIdx.x;  // 512 entry tags
  int tag = k;
  const int lo = s * 16;
  for (int t = lo + 15; t >= lo; --t)
    if (t < len) tag = bp[(size_t)t * KK + tag];
  E[s * KK + k] = (uint16_t)tag;
}

// compose segment maps from the top, then re-walk each segment and emit the path
__global__ void __launch_bounds__(64) k_emit(
    const void* __restrict__ lens, float* __restrict__ out, char* ws) {
  const int len = read_len(lens);
  const uint16_t* bp = (const uint16_t*)(ws + WS_BP);
  const uint16_t* E = (const uint16_t*)(ws + WS_E);
  __shared__ int entry[64];
  const int tid = threadIdx.x;
  if (tid == 0) {
    int st = *((const int*)(ws + WS_BEST));
    for (int s = 63; s >= 0; --s) { entry[s] = st; st = E[s * KK + st]; }
  }
  __syncthreads();
  {
    const int s = tid;
    int st = entry[s];
    for (int t = s * 16 + 15; t >= s * 16; --t) {
      if (t < len) {
        out[1 + t] = (float)st;
        st = bp[(size_t)t * KK + st];
      } else {
        out[1 + t] = -1.0f;
      }
    }
  }
}

extern "C" void kernel_launch(void* const* d_in, const int* in_sizes, int n_in,
                              void* d_out, int out_size, void* d_ws, size_t ws_size,
                              hipStream_t stream) {
  const float* feats = (const float*)d_in[0];
  const float* trans = (const float*)d_in[1];
  const void* lens = d_in[2];
  float* out = (float*)d_out;
  char* ws = (char*)d_ws;
  (void)in_sizes; (void)n_in; (void)out_size; (void)ws_size;

  k_init<<<1, 512, 0, stream>>>(ws);
  k_forward<<<512, 64, 0, stream>>>(feats, trans, lens, out, ws);
  k_walk<<<64, 512, 0, stream>>>(lens, ws);
  k_emit<<<1, 64, 0, stream>>>(lens, out, ws);
}

// Round 4
// 1298.418 us; speedup vs baseline: 1.1651x; 1.1651x over previous
//
#include <hip/hip_runtime.h>
#include <stdint.h>

// Viterbi CRF decode, batch element 63 only (reference returns scores[-1], paths[-1]).
// feats: [64,1024,512] f32, transitions: [512,512] f32, lengths: [64] int.
// out: [0]=score (f32), [1..1024]=path as f32 (-1 for t>=len).
//
// Protocol: 128 waves, FOUR destination rows each (spin pressure on the shared
// fv lines scales with wave count — measured R2/R3: 256 waves=0.61us/step,
// 512 waves=1.42us/step). fv exchanged via 8-deep ring of 512 packed
// (tag<<32 | f32) words, relaxed agent-scope atomics only. No barriers, no
// read-gate (induction: full slot-t implies all waves finished step t-1,
// hence all tag-(t-7) reads are long complete -> overwrite safe).
// Spin re-polls ONLY stale words (per-lane mask) to cut LLC line pressure.

#define KK 512
#define TMAX 1024
#define STARTT 510
#define STOPT 511
#define NEGINF (-10000.0f)
#define DSLOT 8
#define RPW 4      // rows per wave
#define NWG (KK / RPW)  // 128

// ws layout
#define WS_FV 0                      // uint64 fvbuf[8][512]  (32 KB)
#define WS_BEST 32768                // int best
#define WS_BP 40960                  // uint16 bp[1024][512]  (1 MB)
#define WS_E (40960 + 1048576)       // uint16 E[64][512]     (64 KB)

__device__ __forceinline__ int read_len(const void* lp) {
  // lengths may be int32 or int64; int64 little-endian has hi-word 0 at odd int32 slots
  const int* q = (const int*)lp;
  return (q[1] == 0) ? (int)(((const long long*)lp)[63]) : q[63];
}

__global__ void k_init(char* ws) {
  uint64_t* fvb = (uint64_t*)(ws + WS_FV);
  int tid = threadIdx.x;  // 512
  float v = (tid == STARTT) ? 0.0f : NEGINF;
  fvb[tid] = (uint64_t)__float_as_uint(v);  // tag 0 in hi32
#pragma unroll
  for (int b = 1; b < DSLOT; ++b) fvb[b * KK + tid] = 0x7FFFFFFF00000000ull;
}

__global__ void __launch_bounds__(64) k_forward(
    const float* __restrict__ feats, const float* __restrict__ trans,
    const void* __restrict__ lens, float* __restrict__ out, char* ws) {
  const int len = read_len(lens);
  const int R0 = blockIdx.x * RPW;  // rows R0..R0+3
  const int l = threadIdx.x;        // 0..63
  uint64_t* fvb = (uint64_t*)(ws + WS_FV);
  uint16_t* bp = (uint16_t*)(ws + WS_BP);

  // transitions: rows R0..R0+3, cols l+64m — all compile-time indices (registers)
  float tr[RPW][8];
#pragma unroll
  for (int r = 0; r < RPW; ++r)
#pragma unroll
    for (int m = 0; m < 8; ++m)
      tr[r][m] = trans[(size_t)(R0 + r) * KK + l + 64 * m];

  const float* fb = feats + 63ll * TMAX * KK;  // batch 63
  // lane r (r<4) carries feat for row R0+r
  float featNext = (l < RPW) ? fb[R0 + l] : 0.0f;

  for (int t = 0; t < len; ++t) {
    uint64_t* slot = fvb + (size_t)(t & (DSLOT - 1)) * KK;
    uint64_t v[8];
    uint32_t stale = 0xFFu;
    do {
#pragma unroll
      for (int m = 0; m < 8; ++m)
        if (stale & (1u << m))
          v[m] = __hip_atomic_load(&slot[l + 64 * m], __ATOMIC_RELAXED, __HIP_MEMORY_SCOPE_AGENT);
#pragma unroll
      for (int m = 0; m < 8; ++m)
        if ((stale & (1u << m)) && (int)(uint32_t)(v[m] >> 32) == t)
          stale &= ~(1u << m);
    } while (__any(stale != 0));

    float fval[8];
#pragma unroll
    for (int m = 0; m < 8; ++m) fval[m] = __uint_as_float((uint32_t)v[m]);

    const float featCur = featNext;
    if (l < RPW && t + 1 < len) featNext = fb[(size_t)(t + 1) * KK + R0 + l];

    // per-row lane-local tree argmax over m (">=" keeps lower m => lower j),
    // then cross-lane reduce with first-index tie-break
    float bvs[RPW];
    int bjs[RPW];
#pragma unroll
    for (int r = 0; r < RPW; ++r) {
      float c0[8];
#pragma unroll
      for (int m = 0; m < 8; ++m) c0[m] = fval[m] + tr[r][m];
      float v4[4]; int i4[4];
#pragma unroll
      for (int m = 0; m < 4; ++m) {
        const bool L = c0[2 * m] >= c0[2 * m + 1];
        v4[m] = L ? c0[2 * m] : c0[2 * m + 1];
        i4[m] = L ? 2 * m : 2 * m + 1;
      }
      float v2[2]; int i2[2];
#pragma unroll
      for (int m = 0; m < 2; ++m) {
        const bool L = v4[2 * m] >= v4[2 * m + 1];
        v2[m] = L ? v4[2 * m] : v4[2 * m + 1];
        i2[m] = L ? i4[2 * m] : i4[2 * m + 1];
      }
      const bool L = v2[0] >= v2[1];
      bvs[r] = L ? v2[0] : v2[1];
      bjs[r] = l + 64 * (L ? i2[0] : i2[1]);
    }
#pragma unroll
    for (int r = 0; r < RPW; ++r) {
      float bv = bvs[r];
      int bj = bjs[r];
#pragma unroll
      for (int m = 32; m >= 1; m >>= 1) {
        float ov = __shfl_xor(bv, m);
        int oj = __shfl_xor(bj, m);
        if (ov > bv || (ov == bv && oj < bj)) { bv = ov; bj = oj; }
      }
      bvs[r] = bv;
      bjs[r] = bj;
    }
    // lane r publishes row R0+r: 4 contiguous 8B words -> one transaction
    float mybv = bvs[0]; int mybj = bjs[0];
    if (l == 1) { mybv = bvs[1]; mybj = bjs[1]; }
    if (l == 2) { mybv = bvs[2]; mybj = bjs[2]; }
    if (l == 3) { mybv = bvs[3]; mybj = bjs[3]; }
    if (l < RPW) {
      const float vit = mybv + featCur;
      const uint64_t pk = ((uint64_t)(uint32_t)(t + 1) << 32) | (uint64_t)__float_as_uint(vit);
      __hip_atomic_store(&fvb[(size_t)((t + 1) & (DSLOT - 1)) * KK + R0 + l], pk,
                         __ATOMIC_RELAXED, __HIP_MEMORY_SCOPE_AGENT);
      bp[(size_t)t * KK + R0 + l] = (uint16_t)mybj;  // after fv store: off critical path
    }
  }

  if (R0 != 0) return;
  // terminal: score = max_j fv[j] + trans[STOP][j], best = first argmax
  {
    uint64_t* slot = fvb + (size_t)(len & (DSLOT - 1)) * KK;
    uint64_t v[8];
    bool ok;
    do {
#pragma unroll
      for (int m = 0; m < 8; ++m)
        v[m] = __hip_atomic_load(&slot[l + 64 * m], __ATOMIC_RELAXED, __HIP_MEMORY_SCOPE_AGENT);
      ok = true;
#pragma unroll
      for (int m = 0; m < 8; ++m) ok = ok && ((int)(uint32_t)(v[m] >> 32) == len);
    } while (__any(!ok));
    float tv;
    int tj;
#pragma unroll
    for (int m = 0; m < 8; ++m) {
      float x = __uint_as_float((uint32_t)v[m]) + trans[(size_t)STOPT * KK + l + 64 * m];
      if (m == 0) {
        tv = x; tj = l;
      } else if (x > tv) {
        tv = x; tj = l + 64 * m;
      }
    }
#pragma unroll
    for (int m = 32; m >= 1; m >>= 1) {
      float ov = __shfl_xor(tv, m);
      int oj = __shfl_xor(tj, m);
      if (ov > tv || (ov == tv && oj < tj)) { tv = ov; tj = oj; }
    }
    if (l == 0) {
      out[0] = tv;
      *((int*)(ws + WS_BEST)) = tj;
    }
  }
}

// speculative backtrack: per 16-step segment, walk all 512 possible entry tags
__global__ void __launch_bounds__(512) k_walk(const void* __restrict__ lens, char* ws) {
  const int len = read_len(lens);
  const uint16_t* bp = (const uint16_t*)(ws + WS_BP);
  uint16_t* E = (uint16_t*)(ws + WS_E);
  const int s = blockIdx.x;   // 64 segments
  const int k = threadIdx.x;  // 512 entry tags
  int tag = k;
  const int lo = s * 16;
  for (int t = lo + 15; t >= lo; --t)
    if (t < len) tag = bp[(size_t)t * KK + tag];
  E[s * KK + k] = (uint16_t)tag;
}

// compose segment maps from the top, then re-walk each segment and emit the path
__global__ void __launch_bounds__(64) k_emit(
    const void* __restrict__ lens, float* __restrict__ out, char* ws) {
  const int len = read_len(lens);
  const uint16_t* bp = (const uint16_t*)(ws + WS_BP);
  const uint16_t* E = (const uint16_t*)(ws + WS_E);
  __shared__ int entry[64];
  const int tid = threadIdx.x;
  if (tid == 0) {
    int st = *((const int*)(ws + WS_BEST));
    for (int s = 63; s >= 0; --s) { entry[s] = st; st = E[s * KK + st]; }
  }
  __syncthreads();
  {
    const int s = tid;
    int st = entry[s];
    for (int t = s * 16 + 15; t >= s * 16; --t) {
      if (t < len) {
        out[1 + t] = (float)st;
        st = bp[(size_t)t * KK + st];
      } else {
        out[1 + t] = -1.0f;
      }
    }
  }
}

extern "C" void kernel_launch(void* const* d_in, const int* in_sizes, int n_in,
                              void* d_out, int out_size, void* d_ws, size_t ws_size,
                              hipStream_t stream) {
  const float* feats = (const float*)d_in[0];
  const float* trans = (const float*)d_in[1];
  const void* lens = d_in[2];
  float* out = (float*)d_out;
  char* ws = (char*)d_ws;
  (void)in_sizes; (void)n_in; (void)out_size; (void)ws_size;

  k_init<<<1, 512, 0, stream>>>(ws);
  k_forward<<<NWG, 64, 0, stream>>>(feats, trans, lens, out, ws);
  k_walk<<<64, 512, 0, stream>>>(lens, ws);
  k_emit<<<1, 64, 0, stream>>>(lens, out, ws);
}

// Round 5
// 660.007 us; speedup vs baseline: 2.2921x; 1.9673x over previous
//
#include <hip/hip_runtime.h>
#include <stdint.h>

// Viterbi CRF decode, batch element 63 only (reference returns scores[-1], paths[-1]).
// feats: [64,1024,512] f32, transitions: [512,512] f32, lengths: [64] int.
// out: [0]=score (f32), [1..1024]=path as f32 (-1 for t>=len).
//
// Protocol (R2 base + fv replication): 256 waves, 2 destination rows each.
// fv exchanged via ncopy replicas of an 8-deep ring of 512 packed
// (tag<<32 | f32) words, relaxed agent-scope atomics only. Producers store to
// all replicas; consumers poll only replica (w & (ncopy-1)) -> per-LLC-line
// reader count drops 256 -> 256/ncopy (measured R2/R3: detect time scales
// ~linearly with polling-wave count per line).
// No barriers, no read-gate: a complete tag-t slot in ANY replica certifies
// every producer finished step t-1, hence all reads of tag-(t-7) words are
// complete -> depth-8 ring overwrite is safe.
// R4 lesson: keep per-wave registers lean (R4's 4-rows/wave spilled ->
// compiler LDS + 2.3M bank conflicts + 2x regression). This kernel is the
// proven 36-VGPR R2 compute path unchanged.

#define KK 512
#define TMAX 1024
#define STARTT 510
#define STOPT 511
#define NEGINF (-10000.0f)
#define DSLOT 8

// ws layout: bp first, fv replicas last (replica count adapts to ws_size)
#define WS_BP 0                      // uint16 bp[1024][512]  (1 MB)
#define WS_E 1048576                 // uint16 E[64][512]     (64 KB)
#define WS_BEST 1114112              // int best (padded to 64 B)
#define WS_FV 1114176                // uint64 fv[ncopy][8][512]  (ncopy * 32 KB)

__device__ __forceinline__ int read_len(const void* lp) {
  // lengths may be int32 or int64; int64 little-endian has hi-word 0 at odd int32 slots
  const int* q = (const int*)lp;
  return (q[1] == 0) ? (int)(((const long long*)lp)[63]) : q[63];
}

__global__ void k_init(char* ws, int ncopy) {
  uint64_t* fvb = (uint64_t*)(ws + WS_FV);
  const int tid = threadIdx.x;  // 512
  const float v0 = (tid == STARTT) ? 0.0f : NEGINF;
  const uint64_t iv = (uint64_t)__float_as_uint(v0);  // tag 0 in hi32
  for (int rp = 0; rp < ncopy; ++rp) {
    uint64_t* rep = fvb + (size_t)rp * (DSLOT * KK);
    rep[tid] = iv;
    for (int b = 1; b < DSLOT; ++b) rep[b * KK + tid] = 0x7FFFFFFF00000000ull;
  }
}

__global__ void __launch_bounds__(64) k_forward(
    const float* __restrict__ feats, const float* __restrict__ trans,
    const void* __restrict__ lens, float* __restrict__ out, char* ws, int ncopy) {
  const int len = read_len(lens);
  const int w = blockIdx.x;   // 0..255, one wave per WG
  const int l = threadIdx.x;  // 0..63
  const int c = l & 31;
  const int R = 2 * w + (l >> 5);  // my destination row
  uint64_t* fvb = (uint64_t*)(ws + WS_FV);
  uint64_t* myrep = fvb + (size_t)(w & (ncopy - 1)) * (DSLOT * KK);
  uint16_t* bp = (uint16_t*)(ws + WS_BP);

  // transitions slice in registers: row R, cols c+32k
  float tr[16];
#pragma unroll
  for (int k = 0; k < 16; ++k) tr[k] = trans[(size_t)R * KK + c + 32 * k];

  const float* fb = feats + 63ll * TMAX * KK;  // batch 63
  const bool leader = (c == 0);
  float featNext = leader ? fb[R] : 0.0f;

  for (int t = 0; t < len; ++t) {
    uint64_t* slot = myrep + (size_t)(t & (DSLOT - 1)) * KK;
    // spin: lane l owns entries j = l + 64m; wave covers all 512
    uint64_t v[8];
    bool ok;
    do {
#pragma unroll
      for (int m = 0; m < 8; ++m)
        v[m] = __hip_atomic_load(&slot[l + 64 * m], __ATOMIC_RELAXED, __HIP_MEMORY_SCOPE_AGENT);
      ok = true;
#pragma unroll
      for (int m = 0; m < 8; ++m) ok = ok && ((int)(uint32_t)(v[m] >> 32) == t);
    } while (__any(!ok));
    float fvals[8];
#pragma unroll
    for (int m = 0; m < 8; ++m) fvals[m] = __uint_as_float((uint32_t)v[m]);

    const float featCur = featNext;
    if (leader && t + 1 < len) featNext = fb[(size_t)(t + 1) * KK + R];

    // cand j = c + 32k held by lane c+32(k&1), reg k>>1; ascending k = ascending j
    float bv;
    int bj;
#pragma unroll
    for (int k = 0; k < 16; ++k) {
      float fvk = __shfl(fvals[k >> 1], c + 32 * (k & 1));
      float cand = fvk + tr[k];
      if (k == 0) {
        bv = cand; bj = c;
      } else if (cand > bv) {
        bv = cand; bj = c + 32 * k;
      }
    }
    // reduce within 32-lane row group, first-index tie-break
#pragma unroll
    for (int m = 16; m >= 1; m >>= 1) {
      float ov = __shfl_xor(bv, m);
      int oj = __shfl_xor(bj, m);
      if (ov > bv || (ov == bv && oj < bj)) { bv = ov; bj = oj; }
    }
    if (leader) {
      const float vit = bv + featCur;
      const uint64_t pk = ((uint64_t)(uint32_t)(t + 1) << 32) | (uint64_t)__float_as_uint(vit);
      const size_t so = (size_t)((t + 1) & (DSLOT - 1)) * KK + R;
      for (int rp = 0; rp < ncopy; ++rp)
        __hip_atomic_store(&fvb[(size_t)rp * (DSLOT * KK) + so], pk,
                           __ATOMIC_RELAXED, __HIP_MEMORY_SCOPE_AGENT);
      bp[(size_t)t * KK + R] = (uint16_t)bj;  // after fv stores: off critical path
    }
  }

  if (w != 0) return;
  // terminal: score = max_j fv[j] + trans[STOP][j], best = first argmax (replica 0)
  {
    uint64_t* slot = myrep + (size_t)(len & (DSLOT - 1)) * KK;
    uint64_t v[8];
    bool ok;
    do {
#pragma unroll
      for (int m = 0; m < 8; ++m)
        v[m] = __hip_atomic_load(&slot[l + 64 * m], __ATOMIC_RELAXED, __HIP_MEMORY_SCOPE_AGENT);
      ok = true;
#pragma unroll
      for (int m = 0; m < 8; ++m) ok = ok && ((int)(uint32_t)(v[m] >> 32) == len);
    } while (__any(!ok));
    float tv;
    int tj;
#pragma unroll
    for (int m = 0; m < 8; ++m) {
      float x = __uint_as_float((uint32_t)v[m]) + trans[(size_t)STOPT * KK + l + 64 * m];
      if (m == 0) {
        tv = x; tj = l;
      } else if (x > tv) {
        tv = x; tj = l + 64 * m;
      }
    }
#pragma unroll
    for (int m = 32; m >= 1; m >>= 1) {
      float ov = __shfl_xor(tv, m);
      int oj = __shfl_xor(tj, m);
      if (ov > tv || (ov == tv && oj < tj)) { tv = ov; tj = oj; }
    }
    if (l == 0) {
      out[0] = tv;
      *((int*)(ws + WS_BEST)) = tj;
    }
  }
}

// speculative backtrack: per 16-step segment, walk all 512 possible entry tags
__global__ void __launch_bounds__(512) k_walk(const void* __restrict__ lens, char* ws) {
  const int len = read_len(lens);
  const uint16_t* bp = (const uint16_t*)(ws + WS_BP);
  uint16_t* E = (uint16_t*)(ws + WS_E);
  const int s = blockIdx.x;   // 64 segments
  const int k = threadIdx.x;  // 512 entry tags
  int tag = k;
  const int lo = s * 16;
  for (int t = lo + 15; t >= lo; --t)
    if (t < len) tag = bp[(size_t)t * KK + tag];
  E[s * KK + k] = (uint16_t)tag;
}

// compose segment maps from the top, then re-walk each segment and emit the path
__global__ void __launch_bounds__(64) k_emit(
    const void* __restrict__ lens, float* __restrict__ out, char* ws) {
  const int len = read_len(lens);
  const uint16_t* bp = (const uint16_t*)(ws + WS_BP);
  const uint16_t* E = (const uint16_t*)(ws + WS_E);
  __shared__ int entry[64];
  const int tid = threadIdx.x;
  if (tid == 0) {
    int st = *((const int*)(ws + WS_BEST));
    for (int s = 63; s >= 0; --s) { entry[s] = st; st = E[s * KK + st]; }
  }
  __syncthreads();
  {
    const int s = tid;
    int st = entry[s];
    for (int t = s * 16 + 15; t >= s * 16; --t) {
      if (t < len) {
        out[1 + t] = (float)st;
        st = bp[(size_t)t * KK + st];
      } else {
        out[1 + t] = -1.0f;
      }
    }
  }
}

extern "C" void kernel_launch(void* const* d_in, const int* in_sizes, int n_in,
                              void* d_out, int out_size, void* d_ws, size_t ws_size,
                              hipStream_t stream) {
  const float* feats = (const float*)d_in[0];
  const float* trans = (const float*)d_in[1];
  const void* lens = d_in[2];
  float* out = (float*)d_out;
  char* ws = (char*)d_ws;
  (void)in_sizes; (void)n_in; (void)out_size;

  // adapt replica count to available scratch (ncopy=1 degrades to proven R2)
  const size_t base = (size_t)WS_FV;
  int ncopy = 1;
  if (ws_size >= base + 8 * 32768) ncopy = 8;
  else if (ws_size >= base + 4 * 32768) ncopy = 4;
  else if (ws_size >= base + 2 * 32768) ncopy = 2;

  k_init<<<1, 512, 0, stream>>>(ws, ncopy);
  k_forward<<<256, 64, 0, stream>>>(feats, trans, lens, out, ws, ncopy);
  k_walk<<<64, 512, 0, stream>>>(lens, ws);
  k_emit<<<1, 64, 0, stream>>>(lens, out, ws);
}